// Round 7
// baseline (838.069 us; speedup 1.0000x reference)
//
#include <hip/hip_runtime.h>
#include <hip/hip_bf16.h>

typedef _Float16 half8 __attribute__((ext_vector_type(8)));
typedef _Float16 f16x8 __attribute__((ext_vector_type(8)));
typedef __fp16 fp16x2 __attribute__((ext_vector_type(2)));
typedef float f32x16 __attribute__((ext_vector_type(16)));
typedef unsigned uint2v __attribute__((ext_vector_type(2)));

#define NPIX 16384      // H*W
#define NPOOL 4096      // pooled N
#define BN 32768        // B*N
#define KSPLIT 8
#define LOG2E 1.44269504088896340736f
#define THR 4.0f        // defer-max threshold (log2 units): p <= 2^4, f16-safe

__device__ inline f32x16 mfma16(half8 a, half8 b, f32x16 c) {
  return __builtin_amdgcn_mfma_f32_32x32x16_f16(a, b, c, 0, 0, 0);
}

// ---- K1 (fused prep): theta f16 [BN][8]*log2e; phiT f16 [b][M][8]; gT f16 [b][64][M]
__global__ __launch_bounds__(256) void prep_kernel(
    const float* __restrict__ x,
    const float* __restrict__ w_theta, const float* __restrict__ b_theta,
    const float* __restrict__ w_phi, const float* __restrict__ b_phi,
    const float* __restrict__ w_g, const float* __restrict__ b_g,
    _Float16* __restrict__ qf, _Float16* __restrict__ phiT,
    _Float16* __restrict__ gT) {
  __shared__ float xs[64][256];
  int bid = blockIdx.x;
  int oh = bid & 1;
  int pr = (bid >> 1) & 63;
  int b  = bid >> 7;
  int t = threadIdx.x;

  const float* xb = x + (size_t)b * 64 * NPIX + pr * 256;
#pragma unroll 8
  for (int c = 0; c < 64; c++) xs[c][t] = xb[(size_t)c * NPIX + t];
  __syncthreads();

  if (oh == 0) {
    float acc[8];
#pragma unroll
    for (int j = 0; j < 8; j++) acc[j] = b_theta[j];
    for (int c = 0; c < 64; c++) {
      float xv = xs[c][t];
#pragma unroll
      for (int j = 0; j < 8; j++) acc[j] += xv * w_theta[j * 64 + c];
    }
    half8 h;
#pragma unroll
    for (int j = 0; j < 8; j++) h[j] = (_Float16)(acc[j] * LOG2E);
    *(half8*)(qf + ((size_t)b * NPIX + pr * 256 + t) * 8) = h;
  }

  int pos = t & 63;
  int ocg = t >> 6;
  int oc0 = oh * 36 + ocg * 9;
  const float* wrow[9];
  float a0[9], a1[9], a2[9], a3[9];
#pragma unroll
  for (int j = 0; j < 9; j++) {
    int oc = oc0 + j;
    float bv;
    if (oc < 64) { wrow[j] = w_g + oc * 64; bv = b_g[oc]; }
    else         { wrow[j] = w_phi + (oc - 64) * 64; bv = b_phi[oc - 64]; }
    a0[j] = bv; a1[j] = bv; a2[j] = bv; a3[j] = bv;
  }
  for (int c = 0; c < 64; c++) {
    float2 lo = *(const float2*)&xs[c][2 * pos];
    float2 hi = *(const float2*)&xs[c][128 + 2 * pos];
#pragma unroll
    for (int j = 0; j < 9; j++) {
      float wv = wrow[j][c];
      a0[j] += wv * lo.x;
      a1[j] += wv * lo.y;
      a2[j] += wv * hi.x;
      a3[j] += wv * hi.y;
    }
  }
  int m = pr * 64 + pos;
#pragma unroll
  for (int j = 0; j < 9; j++) {
    int oc = oc0 + j;
    float v = fmaxf(fmaxf(a0[j], a1[j]), fmaxf(a2[j], a3[j]));
    if (oc < 64) gT[((size_t)b * 64 + oc) * NPOOL + m] = (_Float16)v;
    else         phiT[((size_t)b * NPOOL + m) * 8 + (oc - 64)] = (_Float16)v;
  }
}

// ---- K2: flash attention partials, in-chunk defer-max online softmax ----
// grid = b(2) x qt(128) x kc(8) = 2048 blocks; 4 waves x 32 queries
__global__ __launch_bounds__(256, 8) void attn_kernel(
    const _Float16* __restrict__ qf, const _Float16* __restrict__ phiT,
    const _Float16* __restrict__ gT,
    float* __restrict__ part_m, float* __restrict__ part_l,
    _Float16* __restrict__ part_o) {
  __shared__ _Float16 lds_g[64 * 64];    // [c row][64 keys], XOR-swizzled 16B slots
  int bx = blockIdx.x;
  int kc = bx & (KSPLIT - 1);
  int qt = (bx >> 3) & 127;
  int b  = bx >> 10;
  int tid = threadIdx.x;
  int w = tid >> 6, lane = tid & 63;
  int q = lane & 31, hi = lane >> 5;
  int qg0 = qt * 128 + w * 32;

  half8 qfrag = {0, 0, 0, 0, 0, 0, 0, 0};
  if (!hi) qfrag = *(const half8*)(qf + ((size_t)b * NPIX + qg0 + q) * 8);

  f32x16 oacc0, oacc1;
#pragma unroll
  for (int i = 0; i < 16; i++) { oacc0[i] = 0.f; oacc1[i] = 0.f; }
  float lsum = 0.f;
  float mrun = 0.f, nm = -0.f;           // running max (pair-shared), its negative

  int kb0 = kc * (NPOOL / KSPLIT);       // 512-key chunk
  for (int step = 0; step < (NPOOL / KSPLIT) / 64; ++step) {
    int kb = kb0 + step * 64;
    __syncthreads();
#pragma unroll
    for (int h = 0; h < 2; ++h) {
      int ch = tid + h * 256;
      int c = ch >> 3, s = ch & 7;
      half8 v = *(const half8*)(gT + ((size_t)b * 64 + c) * NPOOL + kb + 8 * s);
      *(half8*)(lds_g + c * 64 + ((((16 * s) ^ ((c & 7) << 4))) >> 1)) = v;
    }
    __syncthreads();
#pragma unroll
    for (int sub = 0; sub < 2; ++sub) {
      half8 aphi = {0, 0, 0, 0, 0, 0, 0, 0};
      if (!hi) aphi = *(const half8*)(phiT + ((size_t)b * NPOOL + kb + sub * 32 + q) * 8);
      f32x16 sacc;
#pragma unroll
      for (int i = 0; i < 16; i++) sacc[i] = nm;     // C-init = -m_running
      sacc = mfma16(aphi, qfrag, sacc);              // sacc = s - m
      // pair-shared max of the 32 relative scores for this query
      float pm = sacc[0];
#pragma unroll
      for (int i = 1; i < 16; i++) pm = fmaxf(pm, sacc[i]);
      pm = fmaxf(pm, __shfl_xor(pm, 32));
      float p[16];
      if (!__all(pm <= THR)) {                        // rare: raise m, rescale
        float d = fmaxf(pm, 0.f);
        float f = exp2f(-d);
        lsum *= f;
#pragma unroll
        for (int i = 0; i < 16; i++) { oacc0[i] *= f; oacc1[i] *= f; }
        mrun += d; nm = -mrun;
#pragma unroll
        for (int i = 0; i < 16; i++) p[i] = exp2f(sacc[i] - d);
      } else {                                        // common: p in (0, 16]
#pragma unroll
        for (int i = 0; i < 16; i++) p[i] = exp2f(sacc[i]);
      }
#pragma unroll
      for (int halfk = 0; halfk < 2; ++halfk) {
        int pb = halfk * 8;
        fp16x2 h0 = __builtin_amdgcn_cvt_pkrtz(p[pb + 0], p[pb + 1]);
        fp16x2 h1 = __builtin_amdgcn_cvt_pkrtz(p[pb + 2], p[pb + 3]);
        fp16x2 h2 = __builtin_amdgcn_cvt_pkrtz(p[pb + 4], p[pb + 5]);
        fp16x2 h3 = __builtin_amdgcn_cvt_pkrtz(p[pb + 6], p[pb + 7]);
#if __has_builtin(__builtin_amdgcn_fdot2)
        const fp16x2 ones = {(__fp16)1.0f, (__fp16)1.0f};
        lsum = __builtin_amdgcn_fdot2(h0, ones, lsum, false);
        lsum = __builtin_amdgcn_fdot2(h1, ones, lsum, false);
        lsum = __builtin_amdgcn_fdot2(h2, ones, lsum, false);
        lsum = __builtin_amdgcn_fdot2(h3, ones, lsum, false);
#else
        lsum += p[pb + 0] + p[pb + 1] + p[pb + 2] + p[pb + 3];
        lsum += p[pb + 4] + p[pb + 5] + p[pb + 6] + p[pb + 7];
#endif
        unsigned A0 = __builtin_bit_cast(unsigned, h0);
        unsigned A1 = __builtin_bit_cast(unsigned, h1);
        unsigned B0 = __builtin_bit_cast(unsigned, h2);
        unsigned B1 = __builtin_bit_cast(unsigned, h3);
        union { unsigned u[4]; half8 h; } pf;
#if __has_builtin(__builtin_amdgcn_permlane32_swap)
        // swap(A,B): dst = {lo: A_lo, hi: B_lo}, src = {lo: A_hi, hi: B_hi}
        uint2v r0 = __builtin_amdgcn_permlane32_swap(A0, B0, false, false);
        uint2v r1 = __builtin_amdgcn_permlane32_swap(A1, B1, false, false);
        pf.u[0] = r0[0]; pf.u[1] = r1[0]; pf.u[2] = r0[1]; pf.u[3] = r1[1];
#else
        unsigned xA0 = __shfl_xor(A0, 32), xA1 = __shfl_xor(A1, 32);
        unsigned xB0 = __shfl_xor(B0, 32), xB1 = __shfl_xor(B1, 32);
        pf.u[0] = hi ? xB0 : A0;
        pf.u[1] = hi ? xB1 : A1;
        pf.u[2] = hi ? B0 : xA0;
        pf.u[3] = hi ? B1 : xA1;
#endif
        int sread = sub * 4 + halfk * 2 + hi;
#pragma unroll
        for (int ct = 0; ct < 2; ++ct) {
          int row = ct * 32 + q;
          half8 ag = *(const half8*)(lds_g + row * 64 +
                                     (((16 * sread) ^ ((row & 7) << 4)) >> 1));
          if (ct == 0) oacc0 = mfma16(ag, pf.h, oacc0);
          else         oacc1 = mfma16(ag, pf.h, oacc1);
        }
      }
    }
  }
  lsum += __shfl_xor(lsum, 32);
  if (!hi) {
    part_m[(size_t)kc * BN + b * NPIX + qg0 + q] = mrun;
    part_l[(size_t)kc * BN + b * NPIX + qg0 + q] = lsum;
  }
  // part_o f16 layout [kc][b][n][64]; lane packs 4-channel groups -> 8B stores
  _Float16* po = part_o + (((size_t)(kc * 2 + b) * NPIX) + qg0 + q) * 64;
#pragma unroll
  for (int ct = 0; ct < 2; ++ct) {
#pragma unroll
    for (int g = 0; g < 4; ++g) {
      float v0 = ct ? oacc1[4 * g + 0] : oacc0[4 * g + 0];
      float v1 = ct ? oacc1[4 * g + 1] : oacc0[4 * g + 1];
      float v2 = ct ? oacc1[4 * g + 2] : oacc0[4 * g + 2];
      float v3 = ct ? oacc1[4 * g + 3] : oacc0[4 * g + 3];
      uint2v u;
      u[0] = __builtin_bit_cast(unsigned, __builtin_amdgcn_cvt_pkrtz(v0, v1));
      u[1] = __builtin_bit_cast(unsigned, __builtin_amdgcn_cvt_pkrtz(v2, v3));
      *(uint2v*)(po + 32 * ct + 8 * g + 4 * hi) = u;   // ch = (r&3)+8g+4hi+32ct
    }
  }
}

// ---- K3: combine chunks (max-weighted) + residual epilogue ----
// thread = (64 queries x 4 ch-groups); grid = BN/64 = 512 blocks
__global__ __launch_bounds__(256) void reduce_kernel(
    const float* __restrict__ part_m, const float* __restrict__ part_l,
    const _Float16* __restrict__ part_o, const float* __restrict__ x,
    const float* __restrict__ sig, float* __restrict__ out) {
  int t = threadIdx.x;
  int cg = t >> 6;                       // 0..3 -> channels cg*16..+15
  int qi = blockIdx.x * 64 + (t & 63);
  int b = qi >> 14, n = qi & (NPIX - 1);
  float mv[KSPLIT], lv[KSPLIT];
  float mstar = -3e38f;
#pragma unroll
  for (int kc = 0; kc < KSPLIT; kc++) {
    mv[kc] = part_m[(size_t)kc * BN + qi];
    lv[kc] = part_l[(size_t)kc * BN + qi];
    mstar = fmaxf(mstar, mv[kc]);
  }
  float wk[KSPLIT], L = 0.f;
#pragma unroll
  for (int kc = 0; kc < KSPLIT; kc++) {
    wk[kc] = exp2f(mv[kc] - mstar);
    L += lv[kc] * wk[kc];
  }
  float o16[16];
#pragma unroll
  for (int j = 0; j < 16; j++) o16[j] = 0.f;
#pragma unroll
  for (int kc = 0; kc < KSPLIT; kc++) {
    const _Float16* po = part_o + (((size_t)(kc * 2 + b) * NPIX) + n) * 64 + cg * 16;
    f16x8 v0 = *(const f16x8*)po;
    f16x8 v1 = *(const f16x8*)(po + 8);
    float wv = wk[kc];
#pragma unroll
    for (int j = 0; j < 8; j++) {
      o16[j]     += wv * (float)v0[j];
      o16[8 + j] += wv * (float)v1[j];
    }
  }
  float scale = sig[0] / L;
#pragma unroll
  for (int j = 0; j < 16; j++) {
    int c = cg * 16 + j;
    size_t idx = ((size_t)b * 64 + c) * NPIX + n;
    out[idx] = x[idx] + scale * o16[j];
  }
}

extern "C" void kernel_launch(void* const* d_in, const int* in_sizes, int n_in,
                              void* d_out, int out_size, void* d_ws, size_t ws_size,
                              hipStream_t stream) {
  const float* x       = (const float*)d_in[0];
  const float* w_theta = (const float*)d_in[1];
  const float* b_theta = (const float*)d_in[2];
  const float* w_phi   = (const float*)d_in[3];
  const float* b_phi   = (const float*)d_in[4];
  const float* w_g     = (const float*)d_in[5];
  const float* b_g     = (const float*)d_in[6];
  const float* sigma   = (const float*)d_in[7];
  float* out = (float*)d_out;

  // Workspace layout (bytes):
  //   qf     @ 0        : BN*8*2              = 524288
  //   phiT   @ 524288   : 2*NPOOL*8*2         = 131072
  //   gT     @ 655360   : 2*64*NPOOL*2        = 1048576
  //   part_m @ 1703936  : KSPLIT*BN*4         = 1048576
  //   part_l @ 2752512  : KSPLIT*BN*4         = 1048576
  //   part_o @ 3801088  : KSPLIT*2*NPIX*64*2  = 33554432   (total ~37.4 MB)
  char* ws = (char*)d_ws;
  _Float16* qf     = (_Float16*)ws;
  _Float16* phiT   = (_Float16*)(ws + 524288);
  _Float16* gT     = (_Float16*)(ws + 655360);
  float*    part_m = (float*)(ws + 1703936);
  float*    part_l = (float*)(ws + 2752512);
  _Float16* part_o = (_Float16*)(ws + 3801088);

  prep_kernel<<<256, 256, 0, stream>>>(x, w_theta, b_theta, w_phi, b_phi,
                                       w_g, b_g, qf, phiT, gT);
  attn_kernel<<<2 * 128 * KSPLIT, 256, 0, stream>>>(qf, phiT, gT,
                                                    part_m, part_l, part_o);
  reduce_kernel<<<512, 256, 0, stream>>>(part_m, part_l, part_o, x, sigma, out);
}

// Round 8
// 102.648 us; speedup vs baseline: 8.1645x; 8.1645x over previous
//
#include <hip/hip_runtime.h>
#include <hip/hip_bf16.h>

typedef _Float16 half8 __attribute__((ext_vector_type(8)));
typedef _Float16 f16x8 __attribute__((ext_vector_type(8)));
typedef __fp16 fp16x2 __attribute__((ext_vector_type(2)));
typedef float f32x16 __attribute__((ext_vector_type(16)));
typedef unsigned uint2v __attribute__((ext_vector_type(2)));

#define NPIX 16384      // H*W
#define NPOOL 4096      // pooled N
#define BN 32768        // B*N
#define KSPLIT 8
#define LOG2E 1.44269504088896340736f
#define THR 4.0f        // defer-max threshold (log2 units): p <= 2^4, f16-safe

__device__ inline f32x16 mfma16(half8 a, half8 b, f32x16 c) {
  return __builtin_amdgcn_mfma_f32_32x32x16_f16(a, b, c, 0, 0, 0);
}

// ---- K1 (fused prep): theta f16 [BN][8]*log2e; phiT f16 [b][M][8]; gT f16 [b][64][M]
__global__ __launch_bounds__(256) void prep_kernel(
    const float* __restrict__ x,
    const float* __restrict__ w_theta, const float* __restrict__ b_theta,
    const float* __restrict__ w_phi, const float* __restrict__ b_phi,
    const float* __restrict__ w_g, const float* __restrict__ b_g,
    _Float16* __restrict__ qf, _Float16* __restrict__ phiT,
    _Float16* __restrict__ gT) {
  __shared__ float xs[64][256];
  int bid = blockIdx.x;
  int oh = bid & 1;
  int pr = (bid >> 1) & 63;
  int b  = bid >> 7;
  int t = threadIdx.x;

  const float* xb = x + (size_t)b * 64 * NPIX + pr * 256;
#pragma unroll 8
  for (int c = 0; c < 64; c++) xs[c][t] = xb[(size_t)c * NPIX + t];
  __syncthreads();

  if (oh == 0) {
    float acc[8];
#pragma unroll
    for (int j = 0; j < 8; j++) acc[j] = b_theta[j];
    for (int c = 0; c < 64; c++) {
      float xv = xs[c][t];
#pragma unroll
      for (int j = 0; j < 8; j++) acc[j] += xv * w_theta[j * 64 + c];
    }
    half8 h;
#pragma unroll
    for (int j = 0; j < 8; j++) h[j] = (_Float16)(acc[j] * LOG2E);
    *(half8*)(qf + ((size_t)b * NPIX + pr * 256 + t) * 8) = h;
  }

  int pos = t & 63;
  int ocg = t >> 6;
  int oc0 = oh * 36 + ocg * 9;
  const float* wrow[9];
  float a0[9], a1[9], a2[9], a3[9];
#pragma unroll
  for (int j = 0; j < 9; j++) {
    int oc = oc0 + j;
    float bv;
    if (oc < 64) { wrow[j] = w_g + oc * 64; bv = b_g[oc]; }
    else         { wrow[j] = w_phi + (oc - 64) * 64; bv = b_phi[oc - 64]; }
    a0[j] = bv; a1[j] = bv; a2[j] = bv; a3[j] = bv;
  }
  for (int c = 0; c < 64; c++) {
    float2 lo = *(const float2*)&xs[c][2 * pos];
    float2 hi = *(const float2*)&xs[c][128 + 2 * pos];
#pragma unroll
    for (int j = 0; j < 9; j++) {
      float wv = wrow[j][c];
      a0[j] += wv * lo.x;
      a1[j] += wv * lo.y;
      a2[j] += wv * hi.x;
      a3[j] += wv * hi.y;
    }
  }
  int m = pr * 64 + pos;
#pragma unroll
  for (int j = 0; j < 9; j++) {
    int oc = oc0 + j;
    float v = fmaxf(fmaxf(a0[j], a1[j]), fmaxf(a2[j], a3[j]));
    if (oc < 64) gT[((size_t)b * 64 + oc) * NPOOL + m] = (_Float16)v;
    else         phiT[((size_t)b * NPOOL + m) * 8 + (oc - 64)] = (_Float16)v;
  }
}

// ---- K2: flash attention partials, in-chunk defer-max online softmax ----
// grid = b(2) x qt(128) x kc(8) = 2048 blocks; 4 waves x 32 queries
// launch_bounds min-waves=4: round-7's 8 forced a 32-VGPR cap -> accumulator
// spill -> 1.25 GB scratch FETCH, 15x regression. Keep 4.
__global__ __launch_bounds__(256, 4) void attn_kernel(
    const _Float16* __restrict__ qf, const _Float16* __restrict__ phiT,
    const _Float16* __restrict__ gT,
    float* __restrict__ part_m, float* __restrict__ part_l,
    _Float16* __restrict__ part_o) {
  __shared__ _Float16 lds_g[64 * 64];    // [c row][64 keys], XOR-swizzled 16B slots
  int bx = blockIdx.x;
  int kc = bx & (KSPLIT - 1);
  int qt = (bx >> 3) & 127;
  int b  = bx >> 10;
  int tid = threadIdx.x;
  int w = tid >> 6, lane = tid & 63;
  int q = lane & 31, hi = lane >> 5;
  int qg0 = qt * 128 + w * 32;

  half8 qfrag = {0, 0, 0, 0, 0, 0, 0, 0};
  if (!hi) qfrag = *(const half8*)(qf + ((size_t)b * NPIX + qg0 + q) * 8);

  f32x16 oacc0, oacc1;
#pragma unroll
  for (int i = 0; i < 16; i++) { oacc0[i] = 0.f; oacc1[i] = 0.f; }
  float lsum = 0.f;
  float mrun = 0.f, nm = -0.f;           // running max (pair-shared), its negative

  int kb0 = kc * (NPOOL / KSPLIT);       // 512-key chunk
  for (int step = 0; step < (NPOOL / KSPLIT) / 64; ++step) {
    int kb = kb0 + step * 64;
    __syncthreads();
#pragma unroll
    for (int h = 0; h < 2; ++h) {
      int ch = tid + h * 256;
      int c = ch >> 3, s = ch & 7;
      half8 v = *(const half8*)(gT + ((size_t)b * 64 + c) * NPOOL + kb + 8 * s);
      *(half8*)(lds_g + c * 64 + ((((16 * s) ^ ((c & 7) << 4))) >> 1)) = v;
    }
    __syncthreads();
#pragma unroll
    for (int sub = 0; sub < 2; ++sub) {
      half8 aphi = {0, 0, 0, 0, 0, 0, 0, 0};
      if (!hi) aphi = *(const half8*)(phiT + ((size_t)b * NPOOL + kb + sub * 32 + q) * 8);
      f32x16 sacc;
#pragma unroll
      for (int i = 0; i < 16; i++) sacc[i] = nm;     // C-init = -m_running
      sacc = mfma16(aphi, qfrag, sacc);              // sacc = s - m
      // pair-shared max of the 32 relative scores for this query (tree)
      float m01 = fmaxf(fmaxf(sacc[0], sacc[1]), fmaxf(sacc[2], sacc[3]));
      float m23 = fmaxf(fmaxf(sacc[4], sacc[5]), fmaxf(sacc[6], sacc[7]));
      float m45 = fmaxf(fmaxf(sacc[8], sacc[9]), fmaxf(sacc[10], sacc[11]));
      float m67 = fmaxf(fmaxf(sacc[12], sacc[13]), fmaxf(sacc[14], sacc[15]));
      float pm = fmaxf(fmaxf(m01, m23), fmaxf(m45, m67));
      pm = fmaxf(pm, __shfl_xor(pm, 32));
      float p[16];
      if (!__all(pm <= THR)) {                        // rare: raise m, rescale
        float d = fmaxf(pm, 0.f);
        float f = exp2f(-d);
        lsum *= f;
#pragma unroll
        for (int i = 0; i < 16; i++) { oacc0[i] *= f; oacc1[i] *= f; }
        mrun += d; nm = -mrun;
#pragma unroll
        for (int i = 0; i < 16; i++) p[i] = exp2f(sacc[i] - d);
      } else {                                        // common: p in (0, 16]
#pragma unroll
        for (int i = 0; i < 16; i++) p[i] = exp2f(sacc[i]);
      }
#pragma unroll
      for (int halfk = 0; halfk < 2; ++halfk) {
        int pb = halfk * 8;
        fp16x2 h0 = __builtin_amdgcn_cvt_pkrtz(p[pb + 0], p[pb + 1]);
        fp16x2 h1 = __builtin_amdgcn_cvt_pkrtz(p[pb + 2], p[pb + 3]);
        fp16x2 h2 = __builtin_amdgcn_cvt_pkrtz(p[pb + 4], p[pb + 5]);
        fp16x2 h3 = __builtin_amdgcn_cvt_pkrtz(p[pb + 6], p[pb + 7]);
#if __has_builtin(__builtin_amdgcn_fdot2)
        const fp16x2 ones = {(__fp16)1.0f, (__fp16)1.0f};
        lsum = __builtin_amdgcn_fdot2(h0, ones, lsum, false);
        lsum = __builtin_amdgcn_fdot2(h1, ones, lsum, false);
        lsum = __builtin_amdgcn_fdot2(h2, ones, lsum, false);
        lsum = __builtin_amdgcn_fdot2(h3, ones, lsum, false);
#else
        lsum += p[pb + 0] + p[pb + 1] + p[pb + 2] + p[pb + 3];
        lsum += p[pb + 4] + p[pb + 5] + p[pb + 6] + p[pb + 7];
#endif
        unsigned A0 = __builtin_bit_cast(unsigned, h0);
        unsigned A1 = __builtin_bit_cast(unsigned, h1);
        unsigned B0 = __builtin_bit_cast(unsigned, h2);
        unsigned B1 = __builtin_bit_cast(unsigned, h3);
        union { unsigned u[4]; half8 h; } pf;
#if __has_builtin(__builtin_amdgcn_permlane32_swap)
        uint2v r0 = __builtin_amdgcn_permlane32_swap(A0, B0, false, false);
        uint2v r1 = __builtin_amdgcn_permlane32_swap(A1, B1, false, false);
        pf.u[0] = r0[0]; pf.u[1] = r1[0]; pf.u[2] = r0[1]; pf.u[3] = r1[1];
#else
        unsigned xA0 = __shfl_xor(A0, 32), xA1 = __shfl_xor(A1, 32);
        unsigned xB0 = __shfl_xor(B0, 32), xB1 = __shfl_xor(B1, 32);
        pf.u[0] = hi ? xB0 : A0;
        pf.u[1] = hi ? xB1 : A1;
        pf.u[2] = hi ? B0 : xA0;
        pf.u[3] = hi ? B1 : xA1;
#endif
        int sread = sub * 4 + halfk * 2 + hi;
#pragma unroll
        for (int ct = 0; ct < 2; ++ct) {
          int row = ct * 32 + q;
          half8 ag = *(const half8*)(lds_g + row * 64 +
                                     (((16 * sread) ^ ((row & 7) << 4)) >> 1));
          if (ct == 0) oacc0 = mfma16(ag, pf.h, oacc0);
          else         oacc1 = mfma16(ag, pf.h, oacc1);
        }
      }
    }
  }
  lsum += __shfl_xor(lsum, 32);
  if (!hi) {
    part_m[(size_t)kc * BN + b * NPIX + qg0 + q] = mrun;
    part_l[(size_t)kc * BN + b * NPIX + qg0 + q] = lsum;
  }
  // part_o f16 layout [kc][b][n][64]; lane packs 4-channel groups -> 8B stores
  _Float16* po = part_o + (((size_t)(kc * 2 + b) * NPIX) + qg0 + q) * 64;
#pragma unroll
  for (int ct = 0; ct < 2; ++ct) {
#pragma unroll
    for (int g = 0; g < 4; ++g) {
      float v0 = ct ? oacc1[4 * g + 0] : oacc0[4 * g + 0];
      float v1 = ct ? oacc1[4 * g + 1] : oacc0[4 * g + 1];
      float v2 = ct ? oacc1[4 * g + 2] : oacc0[4 * g + 2];
      float v3 = ct ? oacc1[4 * g + 3] : oacc0[4 * g + 3];
      uint2v u;
      u[0] = __builtin_bit_cast(unsigned, __builtin_amdgcn_cvt_pkrtz(v0, v1));
      u[1] = __builtin_bit_cast(unsigned, __builtin_amdgcn_cvt_pkrtz(v2, v3));
      *(uint2v*)(po + 32 * ct + 8 * g + 4 * hi) = u;   // ch = (r&3)+8g+4hi+32ct
    }
  }
}

// ---- K3: combine chunks (max-weighted) + residual epilogue ----
__global__ __launch_bounds__(256) void reduce_kernel(
    const float* __restrict__ part_m, const float* __restrict__ part_l,
    const _Float16* __restrict__ part_o, const float* __restrict__ x,
    const float* __restrict__ sig, float* __restrict__ out) {
  int t = threadIdx.x;
  int cg = t >> 6;                       // 0..3 -> channels cg*16..+15
  int qi = blockIdx.x * 64 + (t & 63);
  int b = qi >> 14, n = qi & (NPIX - 1);
  float mv[KSPLIT], lv[KSPLIT];
  float mstar = -3e38f;
#pragma unroll
  for (int kc = 0; kc < KSPLIT; kc++) {
    mv[kc] = part_m[(size_t)kc * BN + qi];
    lv[kc] = part_l[(size_t)kc * BN + qi];
    mstar = fmaxf(mstar, mv[kc]);
  }
  float wk[KSPLIT], L = 0.f;
#pragma unroll
  for (int kc = 0; kc < KSPLIT; kc++) {
    wk[kc] = exp2f(mv[kc] - mstar);
    L += lv[kc] * wk[kc];
  }
  float o16[16];
#pragma unroll
  for (int j = 0; j < 16; j++) o16[j] = 0.f;
#pragma unroll
  for (int kc = 0; kc < KSPLIT; kc++) {
    const _Float16* po = part_o + (((size_t)(kc * 2 + b) * NPIX) + n) * 64 + cg * 16;
    f16x8 v0 = *(const f16x8*)po;
    f16x8 v1 = *(const f16x8*)(po + 8);
    float wv = wk[kc];
#pragma unroll
    for (int j = 0; j < 8; j++) {
      o16[j]     += wv * (float)v0[j];
      o16[8 + j] += wv * (float)v1[j];
    }
  }
  float scale = sig[0] / L;
#pragma unroll
  for (int j = 0; j < 16; j++) {
    int c = cg * 16 + j;
    size_t idx = ((size_t)b * 64 + c) * NPIX + n;
    out[idx] = x[idx] + scale * o16[j];
  }
}

extern "C" void kernel_launch(void* const* d_in, const int* in_sizes, int n_in,
                              void* d_out, int out_size, void* d_ws, size_t ws_size,
                              hipStream_t stream) {
  const float* x       = (const float*)d_in[0];
  const float* w_theta = (const float*)d_in[1];
  const float* b_theta = (const float*)d_in[2];
  const float* w_phi   = (const float*)d_in[3];
  const float* b_phi   = (const float*)d_in[4];
  const float* w_g     = (const float*)d_in[5];
  const float* b_g     = (const float*)d_in[6];
  const float* sigma   = (const float*)d_in[7];
  float* out = (float*)d_out;

  // Workspace layout (bytes):
  //   qf     @ 0        : BN*8*2              = 524288
  //   phiT   @ 524288   : 2*NPOOL*8*2         = 131072
  //   gT     @ 655360   : 2*64*NPOOL*2        = 1048576
  //   part_m @ 1703936  : KSPLIT*BN*4         = 1048576
  //   part_l @ 2752512  : KSPLIT*BN*4         = 1048576
  //   part_o @ 3801088  : KSPLIT*2*NPIX*64*2  = 33554432   (total ~37.4 MB)
  char* ws = (char*)d_ws;
  _Float16* qf     = (_Float16*)ws;
  _Float16* phiT   = (_Float16*)(ws + 524288);
  _Float16* gT     = (_Float16*)(ws + 655360);
  float*    part_m = (float*)(ws + 1703936);
  float*    part_l = (float*)(ws + 2752512);
  _Float16* part_o = (_Float16*)(ws + 3801088);

  prep_kernel<<<256, 256, 0, stream>>>(x, w_theta, b_theta, w_phi, b_phi,
                                       w_g, b_g, qf, phiT, gT);
  attn_kernel<<<2 * 128 * KSPLIT, 256, 0, stream>>>(qf, phiT, gT,
                                                    part_m, part_l, part_o);
  reduce_kernel<<<512, 256, 0, stream>>>(part_m, part_l, part_o, x, sigma, out);
}